// Round 6
// baseline (227.268 us; speedup 1.0000x reference)
//
#include <hip/hip_runtime.h>

// 21-qubit statevector policy net — per-phase kernels (kernel boundary = HW grid barrier).
// R6: + XCD-pairing data-block swizzle in B pass (co-locate 128B-line sharers on one XCD)
//     + conflict-free LDS swizzle sw(j)=j^(((j>>4)&7)<<1) in both passes.
// ws: psi (2^21 float2, 16MB) | partials (512*22 f32) @16MB
#define NQ 21
#define DIM (1 << NQ)
#define NL 4
#define ADIM 18
#define GB 512   // blocks (2 per CU)
#define NT 512   // threads per block

__device__ __forceinline__ float2 cfma2(float2 u0, float2 a, float2 u1, float2 b) {
    return make_float2(u0.x * a.x - u0.y * a.y + u1.x * b.x - u1.y * b.y,
                       u0.x * a.y + u0.y * a.x + u1.x * b.y + u1.y * b.x);
}

struct GateU { float2 u00, u01, u10, u11; };

__device__ __forceinline__ void bfly(float2& a, float2& b, const GateU& U) {
    float2 na = cfma2(U.u00, a, U.u01, b);
    float2 nb = cfma2(U.u10, a, U.u11, b);
    a = na; b = nb;
}

// LDS bank swizzle: XOR float2-slot bits 1..3 with bits 4..6.
// Balanced (4 lanes/bank = floor) for every sweep stride used here; keeps {2m,2m+1}
// adjacent (mask has no bit0) and float4 alignment (mask is even). Bijection on [0,4096).
__device__ __forceinline__ int sw(int j) { return j ^ (((j >> 4) & 7) << 1); }

// threads 0..20 compute this layer's fused U = RZ*RY*RX into LDS (hidden under global loads)
__device__ __forceinline__ void make_mats(GateU* mats, const float* __restrict__ cp, int layer, int tid) {
    if (tid < NQ) {
        const float* ang = cp + (layer * NQ + tid) * 3;
        float a = ang[0], b = ang[1], c = ang[2];
        float ca = cosf(0.5f * a), sa = sinf(0.5f * a);
        float cb = cosf(0.5f * b), sb = sinf(0.5f * b);
        float cc = cosf(0.5f * c), sc = sinf(0.5f * c);
        float2 m00 = make_float2(cb * ca,  sb * sa);
        float2 m01 = make_float2(-sb * ca, -cb * sa);
        float2 m10 = make_float2(sb * ca,  -cb * sa);
        float2 m11 = make_float2(cb * ca,  -sb * sa);
        GateU U;
        U.u00 = make_float2(cc * m00.x + sc * m00.y, cc * m00.y - sc * m00.x);
        U.u01 = make_float2(cc * m01.x + sc * m01.y, cc * m01.y - sc * m01.x);
        U.u10 = make_float2(cc * m10.x - sc * m10.y, cc * m10.y + sc * m10.x);
        U.u11 = make_float2(cc * m11.x - sc * m11.y, cc * m11.y + sc * m11.x);
        mats[tid] = U;
    }
}

// B phase: h = bits 12..20 (qubits 0..8), l = bits 0..2; data-block = bits 3..11.
// dblk swizzle: data chunks d and d^1 share a 128B line -> assign to HW blocks b, b+8 (same XCD).
__global__ __launch_bounds__(NT, 4) void k_passB(const float* __restrict__ state,
                                                 float2* __restrict__ psi,
                                                 const float* __restrict__ cp, int layer) {
    __shared__ float2 tile[4096];
    __shared__ GateU mats[NQ];
    const int tid = threadIdx.x;
    const int blk = (blockIdx.x & 7) * 64 + (blockIdx.x >> 3);   // data-block id
    float4* psi4 = (float4*)psi;
    float4* t4 = (float4*)tile;

    if (layer == 0) {
        const float4* s4 = (const float4*)state;
        for (int it = 0; it < 2; ++it) {
            int f2 = it * NT + tid;
            int h = f2 >> 1, c2 = f2 & 1;
            float4 w = s4[(h << 10) | (blk << 1) | c2];
            int j = 8 * h + 4 * c2;            // float2 slot of first element
            t4[sw(j) >> 1]     = make_float4(w.x, 0.f, w.y, 0.f);
            t4[sw(j + 2) >> 1] = make_float4(w.z, 0.f, w.w, 0.f);
        }
        make_mats(mats, cp, layer, tid);
        __syncthreads();
        for (int kb = 0; kb <= 8; ++kb) {   // h-bit kb -> qubit 8-kb
            GateU U = mats[8 - kb];
            for (int it = 0; it < 4; ++it) {
                int p = it * NT + tid;
                int l = p & 7, hp = p >> 3;
                int h0 = ((hp >> kb) << (kb + 1)) | (hp & ((1 << kb) - 1));
                int i0 = h0 * 8 + l;
                bfly(tile[sw(i0)], tile[sw(i0 + (8 << kb))], U);
            }
            __syncthreads();
        }
    } else {
        float2 v[8];
        float4 w[4];
        for (int i = 0; i < 4; ++i) {
            int f = i * NT + tid;
            int h = f >> 2, c = f & 3;
            w[i] = psi4[(h << 11) | (blk << 2) | c];
        }
        make_mats(mats, cp, layer, tid);
        __syncthreads();
        // c4 (prev layer's wrap CNOT(0->q20)): l odd => h bit8 flip = slot i^2
#pragma unroll
        for (int i = 0; i < 4; ++i) {
            v[2 * i]     = make_float2(w[i].x, w[i].y);
            v[2 * i + 1] = make_float2(w[i ^ 2].z, w[i ^ 2].w);
        }
        // register gates: qubit 0 (h bit8 = slot bit2), qubit 1 (h bit7 = slot bit1)
        GateU U0 = mats[0];
#pragma unroll
        for (int s = 0; s < 8; ++s) if (!(s & 4)) bfly(v[s], v[s | 4], U0);
        GateU U1 = mats[1];
#pragma unroll
        for (int s = 0; s < 8; ++s) if (!(s & 2)) bfly(v[s], v[s | 2], U1);
        for (int i = 0; i < 4; ++i)
            t4[sw(2 * (i * NT + tid)) >> 1] =
                make_float4(v[2 * i].x, v[2 * i].y, v[2 * i + 1].x, v[2 * i + 1].y);
        __syncthreads();
        for (int kb = 0; kb <= 6; ++kb) {   // qubits 8..2 in LDS
            GateU U = mats[8 - kb];
            for (int it = 0; it < 4; ++it) {
                int p = it * NT + tid;
                int l = p & 7, hp = p >> 3;
                int h0 = ((hp >> kb) << (kb + 1)) | (hp & ((1 << kb) - 1));
                int i0 = h0 * 8 + l;
                bfly(tile[sw(i0)], tile[sw(i0 + (8 << kb))], U);
            }
            __syncthreads();
        }
    }
    // store: src h = h ^ ((h>>1)&0xFF) for layers 0..2 (B-local CNOT chain), identity for layer 3
    int srcmask = (layer < 3) ? 0xFF : 0;
    for (int i = 0; i < 4; ++i) {
        int f = i * NT + tid;
        int h = f >> 2, c = f & 3;
        int hs = h ^ ((h >> 1) & srcmask);
        int j = sw(hs * 8 + 2 * c);
        float2 e0 = tile[j], e1 = tile[j + 1];
        psi4[(h << 11) | (blk << 2) | c] = make_float4(e0.x, e0.y, e1.x, e1.y);
    }
}

// A phase: bits 0..11 local (qubits 9..20); block = bits 12..20 (contiguous -> no swizzle needed).
__global__ __launch_bounds__(NT, 4) void k_passA(float2* __restrict__ psi,
                                                 const float* __restrict__ cp, int layer,
                                                 float* __restrict__ partials) {
    __shared__ float2 tile[4096];
    __shared__ GateU mats[NQ];
    const int tid = threadIdx.x, blk = blockIdx.x;
    float4* psi4 = (float4*)psi;
    float4* t4 = (float4*)tile;

    {
        const float4* ga = psi4 + (size_t)blk * 2048;
        float2 v[8];
        float4 w[4];
        for (int i = 0; i < 4; ++i) w[i] = ga[i * NT + tid];
        make_mats(mats, cp, layer, tid);
        __syncthreads();
#pragma unroll
        for (int i = 0; i < 4; ++i) {
            v[2 * i]     = make_float2(w[i].x, w[i].y);
            v[2 * i + 1] = make_float2(w[i].z, w[i].w);
        }
        // register gates: q20 (bit0 = slot bit0), q10 (bit10 = slot bit1), q9 (bit11 = slot bit2)
        GateU U20 = mats[20];
#pragma unroll
        for (int s = 0; s < 8; s += 2) bfly(v[s], v[s + 1], U20);
        GateU U10 = mats[10];
#pragma unroll
        for (int s = 0; s < 8; ++s) if (!(s & 2)) bfly(v[s], v[s | 2], U10);
        GateU U9 = mats[9];
#pragma unroll
        for (int s = 0; s < 8; ++s) if (!(s & 4)) bfly(v[s], v[s | 4], U9);
        for (int i = 0; i < 4; ++i)
            t4[sw(2 * (i * NT + tid)) >> 1] =
                make_float4(v[2 * i].x, v[2 * i].y, v[2 * i + 1].x, v[2 * i + 1].y);
    }
    __syncthreads();
    for (int k = 1; k <= 9; ++k) {          // qubits 19..11 in LDS
        GateU U = mats[20 - k];
        int m = 1 << k;
        for (int it = 0; it < 4; ++it) {
            int p = it * NT + tid;
            int i0 = ((p >> k) << (k + 1)) | (p & (m - 1));
            bfly(tile[sw(i0)], tile[sw(i0 | m)], U);
        }
        __syncthreads();
    }
    if (layer < 3) {
        // boundary CNOT (ctrl = stored bit12 = blk&1, tgt bit11) then A-local chain, as gather
        float4* oa = psi4 + (size_t)blk * 2048;
        int cb = (blk & 1) << 11;
        for (int i = 0; i < 4; ++i) {
            int f = i * NT + tid;
            int s0 = ((2 * f) ^ (f & 0x7FF)) ^ cb;
            float2 e0 = tile[sw(s0)], e1 = tile[sw(s0 ^ 1)];
            oa[f] = make_float4(e0.x, e0.y, e1.x, e1.y);
        }
    } else {
        // measurement: total + per-qubit ones sums (normalization folded in at k_final)
        float tot = 0.f, ones[NQ];
#pragma unroll
        for (int q = 0; q < NQ; ++q) ones[q] = 0.f;
        for (int it = 0; it < 8; ++it) {
            int j = it * NT + tid;
            float2 a2 = tile[sw(j)];
            float pr = a2.x * a2.x + a2.y * a2.y;
            int gidx = (blk << 12) | j;
            tot += pr;
#pragma unroll
            for (int q = 0; q < NQ; ++q)
                ones[q] += pr * (float)((gidx >> (20 - q)) & 1);
        }
        for (int off = 32; off; off >>= 1) {
            tot += __shfl_down(tot, off, 64);
#pragma unroll
            for (int q = 0; q < NQ; ++q) ones[q] += __shfl_down(ones[q], off, 64);
        }
        __syncthreads();
        float* red = (float*)tile;
        int wv = tid >> 6, ln = tid & 63;
        if (ln == 0) {
            red[wv * 22 + 21] = tot;
#pragma unroll
            for (int q = 0; q < NQ; ++q) red[wv * 22 + q] = ones[q];
        }
        __syncthreads();
        if (tid < 22) {
            float s = 0.f;
            for (int wvi = 0; wvi < 8; ++wvi) s += red[wvi * 22 + tid];
            partials[blk * 22 + tid] = s;
        }
    }
}

// Reduce 512 partial rows -> meas -> head -> softmax
__global__ __launch_bounds__(NT) void k_final(const float* __restrict__ partials,
                                              const float* __restrict__ head_w,
                                              const float* __restrict__ head_b,
                                              float* __restrict__ out) {
    __shared__ float red[640];
    __shared__ float meas[NQ];
    __shared__ float lg[ADIM];
    int tid = threadIdx.x;
    int col = tid % 22, grp = tid / 22;
    if (tid < 506) {
        float s = 0.f;
        for (int r = grp; r < GB; r += 23) s += partials[r * 22 + col];
        red[grp * 22 + col] = s;
    }
    __syncthreads();
    if (tid < 22) {
        float t2 = 0.f;
        for (int g = 0; g < 23; ++g) t2 += red[g * 22 + tid];
        red[600 + tid] = t2;
    }
    __syncthreads();
    if (tid < NQ) {
        float tot = red[600 + 21];
        meas[tid] = (tot > 0.f) ? (1.f - 2.f * red[600 + tid] / tot) : 1.f;
    }
    __syncthreads();
    if (tid < ADIM) {
        float s2 = head_b[tid];
        for (int q = 0; q < NQ; ++q) s2 += head_w[tid * NQ + q] * meas[q];
        lg[tid] = s2;
    }
    __syncthreads();
    if (tid == 0) {
        float m = lg[0];
        for (int a = 1; a < ADIM; ++a) m = fmaxf(m, lg[a]);
        float ssum = 0.f;
        for (int a = 0; a < ADIM; ++a) ssum += expf(lg[a] - m);
        float inv = 1.f / ssum;
        for (int a = 0; a < ADIM; ++a) out[a] = expf(lg[a] - m) * inv;
    }
}

extern "C" void kernel_launch(void* const* d_in, const int* in_sizes, int n_in,
                              void* d_out, int out_size, void* d_ws, size_t ws_size,
                              hipStream_t stream) {
    const float* state   = (const float*)d_in[0];
    const float* cparams = (const float*)d_in[1];
    const float* head_w  = (const float*)d_in[2];
    const float* head_b  = (const float*)d_in[3];
    float* out = (float*)d_out;

    float2* psi      = (float2*)d_ws;
    float*  partials = (float*)((char*)d_ws + (size_t)DIM * 8);

    for (int layer = 0; layer < NL; ++layer) {
        k_passB<<<GB, NT, 0, stream>>>(state, psi, cparams, layer);
        k_passA<<<GB, NT, 0, stream>>>(psi, cparams, layer, partials);
    }
    k_final<<<1, NT, 0, stream>>>(partials, head_w, head_b, out);
}

// Round 7
// 207.867 us; speedup vs baseline: 1.0933x; 1.0933x over previous
//
#include <hip/hip_runtime.h>

// 21-qubit statevector policy net — per-phase kernels.
// R7: radix-8 register rounds (3 gates per LDS round-trip) — LDS traffic ~2.2x cut.
//     XCD dblk swizzle reverted (R6 regression suspect). sw() LDS swizzle retained
//     (required: round strides would otherwise hit 2-bank aliasing).
// ws: psi (2^21 float2, 16MB) | partials (512*22 f32) @16MB
#define NQ 21
#define DIM (1 << NQ)
#define NL 4
#define ADIM 18
#define GB 512   // blocks (2 per CU)
#define NT 512   // threads per block

__device__ __forceinline__ float2 cfma2(float2 u0, float2 a, float2 u1, float2 b) {
    return make_float2(u0.x * a.x - u0.y * a.y + u1.x * b.x - u1.y * b.y,
                       u0.x * a.y + u0.y * a.x + u1.x * b.y + u1.y * b.x);
}

struct GateU { float2 u00, u01, u10, u11; };

__device__ __forceinline__ void bfly(float2& a, float2& b, const GateU& U) {
    float2 na = cfma2(U.u00, a, U.u01, b);
    float2 nb = cfma2(U.u10, a, U.u11, b);
    a = na; b = nb;
}

// LDS bank swizzle: XOR float2-slot bits 1..3 with bits 4..6. Keeps {2m,2m+1}
// adjacent and float4 alignment. Gives 4-lanes/bank (b64 floor) for every round stride.
__device__ __forceinline__ int sw(int j) { return j ^ (((j >> 4) & 7) << 1); }

// threads 0..20 compute this layer's fused U = RZ*RY*RX (hidden under global loads)
__device__ __forceinline__ void make_mats(GateU* mats, const float* __restrict__ cp, int layer, int tid) {
    if (tid < NQ) {
        const float* ang = cp + (layer * NQ + tid) * 3;
        float a = ang[0], b = ang[1], c = ang[2];
        float ca = cosf(0.5f * a), sa = sinf(0.5f * a);
        float cb = cosf(0.5f * b), sb = sinf(0.5f * b);
        float cc = cosf(0.5f * c), sc = sinf(0.5f * c);
        float2 m00 = make_float2(cb * ca,  sb * sa);
        float2 m01 = make_float2(-sb * ca, -cb * sa);
        float2 m10 = make_float2(sb * ca,  -cb * sa);
        float2 m11 = make_float2(cb * ca,  -sb * sa);
        GateU U;
        U.u00 = make_float2(cc * m00.x + sc * m00.y, cc * m00.y - sc * m00.x);
        U.u01 = make_float2(cc * m01.x + sc * m01.y, cc * m01.y - sc * m01.x);
        U.u10 = make_float2(cc * m10.x - sc * m10.y, cc * m10.y + sc * m10.x);
        U.u11 = make_float2(cc * m11.x - sc * m11.y, cc * m11.y + sc * m11.x);
        mats[tid] = U;
    }
}

// One radix-8 round: thread owns slot bits {g,g+1,g+2}; gates Ua(bit g), Ub(g+1), Uc(g+2)
// applied wholly in registers; one LDS read+write of the full tile per 3 gates.
__device__ __forceinline__ void round3(float2* tile, int tid, int g,
                                       GateU Ua, GateU Ub, GateU Uc) {
    int bl = (1 << g) - 1;
    int base = (tid & bl) | ((tid >> g) << (g + 3));
    float2 v[8];
#pragma unroll
    for (int j = 0; j < 8; ++j) v[j] = tile[sw(base + (j << g))];
#pragma unroll
    for (int s = 0; s < 8; s += 2) bfly(v[s], v[s + 1], Ua);
#pragma unroll
    for (int s = 0; s < 8; ++s) if (!(s & 2)) bfly(v[s], v[s | 2], Ub);
#pragma unroll
    for (int s = 0; s < 8; ++s) if (!(s & 4)) bfly(v[s], v[s | 4], Uc);
#pragma unroll
    for (int j = 0; j < 8; ++j) tile[sw(base + (j << g))] = v[j];
    __syncthreads();
}

// B phase: slot = h*8 + l; h = global bits 12..20 (qubits 0..8), l = bits 0..2.
// slot bit s (s>=3) <-> qubit 11-s.
__global__ __launch_bounds__(NT, 4) void k_passB(const float* __restrict__ state,
                                                 float2* __restrict__ psi,
                                                 const float* __restrict__ cp, int layer) {
    __shared__ float2 tile[4096];
    __shared__ GateU mats[NQ];
    const int tid = threadIdx.x, blk = blockIdx.x;
    float4* psi4 = (float4*)psi;
    float4* t4 = (float4*)tile;

    if (layer == 0) {
        const float4* s4 = (const float4*)state;
        for (int it = 0; it < 2; ++it) {
            int f2 = it * NT + tid;
            int h = f2 >> 1, c2 = f2 & 1;
            float4 w = s4[(h << 10) | (blk << 1) | c2];
            int j = 8 * h + 4 * c2;
            t4[sw(j) >> 1]     = make_float4(w.x, 0.f, w.y, 0.f);
            t4[sw(j + 2) >> 1] = make_float4(w.z, 0.f, w.w, 0.f);
        }
        make_mats(mats, cp, layer, tid);
        __syncthreads();
        round3(tile, tid, 3, mats[8], mats[7], mats[6]);   // q8,q7,q6
        round3(tile, tid, 6, mats[5], mats[4], mats[3]);   // q5,q4,q3
        round3(tile, tid, 9, mats[2], mats[1], mats[0]);   // q2,q1,q0
    } else {
        float2 v[8];
        float4 w[4];
        for (int i = 0; i < 4; ++i) {
            int f = i * NT + tid;
            int h = f >> 2, c = f & 3;
            w[i] = psi4[(h << 11) | (blk << 2) | c];
        }
        make_mats(mats, cp, layer, tid);
        __syncthreads();
        // c4 (prev layer's wrap CNOT(0->q20)): odd slot => slot bit11 flip = w[i^2]
#pragma unroll
        for (int i = 0; i < 4; ++i) {
            v[2 * i]     = make_float2(w[i].x, w[i].y);
            v[2 * i + 1] = make_float2(w[i ^ 2].z, w[i ^ 2].w);
        }
        // register gates: q0 (slot bit11 = v bit2), q1 (slot bit10 = v bit1)
        GateU U0 = mats[0];
#pragma unroll
        for (int s = 0; s < 8; ++s) if (!(s & 4)) bfly(v[s], v[s | 4], U0);
        GateU U1 = mats[1];
#pragma unroll
        for (int s = 0; s < 8; ++s) if (!(s & 2)) bfly(v[s], v[s | 2], U1);
        for (int i = 0; i < 4; ++i)
            t4[sw(2 * (i * NT + tid)) >> 1] =
                make_float4(v[2 * i].x, v[2 * i].y, v[2 * i + 1].x, v[2 * i + 1].y);
        __syncthreads();
        round3(tile, tid, 3, mats[8], mats[7], mats[6]);   // q8,q7,q6
        round3(tile, tid, 6, mats[5], mats[4], mats[3]);   // q5,q4,q3
        {   // lone sweep: q2 (slot bit9)
            GateU U = mats[2];
            for (int it = 0; it < 4; ++it) {
                int p = it * NT + tid;                     // 2048 pairs
                int i0 = ((p >> 9) << 10) | (p & 511);
                bfly(tile[sw(i0)], tile[sw(i0 | 512)], U);
            }
            __syncthreads();
        }
    }
    // store: src h = h ^ ((h>>1)&0xFF) for layers 0..2 (B-local CNOT chain), identity layer 3
    int srcmask = (layer < 3) ? 0xFF : 0;
    for (int i = 0; i < 4; ++i) {
        int f = i * NT + tid;
        int h = f >> 2, c = f & 3;
        int hs = h ^ ((h >> 1) & srcmask);
        int j = sw(hs * 8 + 2 * c);
        float2 e0 = tile[j], e1 = tile[j + 1];
        psi4[(h << 11) | (blk << 2) | c] = make_float4(e0.x, e0.y, e1.x, e1.y);
    }
}

// A phase: bits 0..11 local (qubits 9..20, slot bit k <-> qubit 20-k); block = bits 12..20.
__global__ __launch_bounds__(NT, 4) void k_passA(float2* __restrict__ psi,
                                                 const float* __restrict__ cp, int layer,
                                                 float* __restrict__ partials) {
    __shared__ float2 tile[4096];
    __shared__ GateU mats[NQ];
    const int tid = threadIdx.x, blk = blockIdx.x;
    float4* psi4 = (float4*)psi;
    float4* t4 = (float4*)tile;

    {
        const float4* ga = psi4 + (size_t)blk * 2048;
        float2 v[8];
        float4 w[4];
        for (int i = 0; i < 4; ++i) w[i] = ga[i * NT + tid];
        make_mats(mats, cp, layer, tid);
        __syncthreads();
#pragma unroll
        for (int i = 0; i < 4; ++i) {
            v[2 * i]     = make_float2(w[i].x, w[i].y);
            v[2 * i + 1] = make_float2(w[i].z, w[i].w);
        }
        // register gates: q20 (slot bit0), q10 (slot bit10 = v bit1), q9 (slot bit11 = v bit2)
        GateU U20 = mats[20];
#pragma unroll
        for (int s = 0; s < 8; s += 2) bfly(v[s], v[s + 1], U20);
        GateU U10 = mats[10];
#pragma unroll
        for (int s = 0; s < 8; ++s) if (!(s & 2)) bfly(v[s], v[s | 2], U10);
        GateU U9 = mats[9];
#pragma unroll
        for (int s = 0; s < 8; ++s) if (!(s & 4)) bfly(v[s], v[s | 4], U9);
        for (int i = 0; i < 4; ++i)
            t4[sw(2 * (i * NT + tid)) >> 1] =
                make_float4(v[2 * i].x, v[2 * i].y, v[2 * i + 1].x, v[2 * i + 1].y);
    }
    __syncthreads();
    round3(tile, tid, 1, mats[19], mats[18], mats[17]);    // q19,q18,q17
    round3(tile, tid, 4, mats[16], mats[15], mats[14]);    // q16,q15,q14
    round3(tile, tid, 7, mats[13], mats[12], mats[11]);    // q13,q12,q11

    if (layer < 3) {
        // boundary CNOT (ctrl = stored bit12 = blk&1, tgt bit11) then A-local chain, as gather
        float4* oa = psi4 + (size_t)blk * 2048;
        int cb = (blk & 1) << 11;
        for (int i = 0; i < 4; ++i) {
            int f = i * NT + tid;
            int s0 = ((2 * f) ^ (f & 0x7FF)) ^ cb;
            float2 e0 = tile[sw(s0)], e1 = tile[sw(s0 ^ 1)];
            oa[f] = make_float4(e0.x, e0.y, e1.x, e1.y);
        }
    } else {
        // measurement: total + per-qubit ones sums (normalization folded in at k_final)
        float tot = 0.f, ones[NQ];
#pragma unroll
        for (int q = 0; q < NQ; ++q) ones[q] = 0.f;
        for (int it = 0; it < 8; ++it) {
            int j = it * NT + tid;
            float2 a2 = tile[sw(j)];
            float pr = a2.x * a2.x + a2.y * a2.y;
            int gidx = (blk << 12) | j;
            tot += pr;
#pragma unroll
            for (int q = 0; q < NQ; ++q)
                ones[q] += pr * (float)((gidx >> (20 - q)) & 1);
        }
        for (int off = 32; off; off >>= 1) {
            tot += __shfl_down(tot, off, 64);
#pragma unroll
            for (int q = 0; q < NQ; ++q) ones[q] += __shfl_down(ones[q], off, 64);
        }
        __syncthreads();
        float* red = (float*)tile;
        int wv = tid >> 6, ln = tid & 63;
        if (ln == 0) {
            red[wv * 22 + 21] = tot;
#pragma unroll
            for (int q = 0; q < NQ; ++q) red[wv * 22 + q] = ones[q];
        }
        __syncthreads();
        if (tid < 22) {
            float s = 0.f;
            for (int wvi = 0; wvi < 8; ++wvi) s += red[wvi * 22 + tid];
            partials[blk * 22 + tid] = s;
        }
    }
}

// Reduce 512 partial rows -> meas -> head -> softmax
__global__ __launch_bounds__(NT) void k_final(const float* __restrict__ partials,
                                              const float* __restrict__ head_w,
                                              const float* __restrict__ head_b,
                                              float* __restrict__ out) {
    __shared__ float red[640];
    __shared__ float meas[NQ];
    __shared__ float lg[ADIM];
    int tid = threadIdx.x;
    int col = tid % 22, grp = tid / 22;
    if (tid < 506) {
        float s = 0.f;
        for (int r = grp; r < GB; r += 23) s += partials[r * 22 + col];
        red[grp * 22 + col] = s;
    }
    __syncthreads();
    if (tid < 22) {
        float t2 = 0.f;
        for (int g = 0; g < 23; ++g) t2 += red[g * 22 + tid];
        red[600 + tid] = t2;
    }
    __syncthreads();
    if (tid < NQ) {
        float tot = red[600 + 21];
        meas[tid] = (tot > 0.f) ? (1.f - 2.f * red[600 + tid] / tot) : 1.f;
    }
    __syncthreads();
    if (tid < ADIM) {
        float s2 = head_b[tid];
        for (int q = 0; q < NQ; ++q) s2 += head_w[tid * NQ + q] * meas[q];
        lg[tid] = s2;
    }
    __syncthreads();
    if (tid == 0) {
        float m = lg[0];
        for (int a = 1; a < ADIM; ++a) m = fmaxf(m, lg[a]);
        float ssum = 0.f;
        for (int a = 0; a < ADIM; ++a) ssum += expf(lg[a] - m);
        float inv = 1.f / ssum;
        for (int a = 0; a < ADIM; ++a) out[a] = expf(lg[a] - m) * inv;
    }
}

extern "C" void kernel_launch(void* const* d_in, const int* in_sizes, int n_in,
                              void* d_out, int out_size, void* d_ws, size_t ws_size,
                              hipStream_t stream) {
    const float* state   = (const float*)d_in[0];
    const float* cparams = (const float*)d_in[1];
    const float* head_w  = (const float*)d_in[2];
    const float* head_b  = (const float*)d_in[3];
    float* out = (float*)d_out;

    float2* psi      = (float2*)d_ws;
    float*  partials = (float*)((char*)d_ws + (size_t)DIM * 8);

    for (int layer = 0; layer < NL; ++layer) {
        k_passB<<<GB, NT, 0, stream>>>(state, psi, cparams, layer);
        k_passA<<<GB, NT, 0, stream>>>(psi, cparams, layer, partials);
    }
    k_final<<<1, NT, 0, stream>>>(partials, head_w, head_b, out);
}